// Round 6
// baseline (463.646 us; speedup 1.0000x reference)
//
#include <hip/hip_runtime.h>
#include <hip/hip_bf16.h>

#define BB 64
#define NN 64
#define CH 128
#define ICI 129
#define PIX_PER_B (NN*NN)
#define NPIX (BB*PIX_PER_B)
#define INV63 (1.0f/63.0f)
#define INV3969 (1.0f/3969.0f)
#define XT 8
#define XTL 4

typedef __attribute__((ext_vector_type(8))) __bf16 bfv8;
typedef __attribute__((ext_vector_type(4))) float fv4;

__device__ inline unsigned short bfr(float x) {
    __hip_bfloat16 h = __float2bfloat16(x);
    return *reinterpret_cast<unsigned short*>(&h);
}

// ---------- weight transform: Wp (bf16 GEMM weights), M (bias GEMM weights), w0 ----------
__global__ void wprep(const float* w2a, const float* w3a, const float* w4a,
                      const float* w2b, const float* w3b, const float* w4b,
                      __hip_bfloat16* Wp, float* Mbuf, float* w0buf) {
    int bid = blockIdx.x;           // 0..5 = br*3+l
    int br = bid / 3, l = bid % 3;
    const float* w = (br == 0) ? (l == 0 ? w2a : (l == 1 ? w3a : w4a))
                               : (l == 0 ? w2b : (l == 1 ? w3b : w4b));
    __hip_bfloat16* dst = Wp + (size_t)bid * CH * CH;
    for (int idx = threadIdx.x; idx < CH * CH; idx += blockDim.x) {
        int o = idx >> 7, j = idx & 127;
        int c = j & 31, grp = j >> 5;
        float v;
        if (grp == 0)      v =  w[o * ICI + 1 + c];
        else if (grp == 1) v = -w[o * ICI + 33 + c] * INV63;
        else if (grp == 2) v = -w[o * ICI + 65 + c] * INV63;
        else               v =  w[o * ICI + 97 + c] * INV3969;
        dst[idx] = __float2bfloat16(v);
    }
    float* M = Mbuf + (size_t)bid * 160 * 128;
    for (int idx = threadIdx.x; idx < 160 * 128; idx += blockDim.x) {
        int c = idx >> 7, o = idx & 127;
        float v;
        if (c < 32)       v =  w[o * ICI + 65 + c] * INV63;
        else if (c < 64)  v = -w[o * ICI + 97 + (c - 32)] * INV3969;
        else if (c < 96)  v =  w[o * ICI + 97 + (c - 64)] * INV3969;
        else if (c < 128) v =  w[o * ICI + 33 + (c - 96)] * INV63;
        else              v = -w[o * ICI + 97 + (c - 128)] * INV3969;
        M[idx] = v;
    }
    if (threadIdx.x < 128) w0buf[bid * 128 + threadIdx.x] = w[threadIdx.x * ICI];
}

// ---------- layer 1, vectorized, fused rowsum, no LDS ----------
__global__ __launch_bounds__(512) void e1k(const float* channel,
        const float* w1a, const float* b1a, const float* w1b, const float* b1b,
        __hip_bfloat16* y, float* rowsum, int br0) {
    int slot = blockIdx.y, br = br0 + slot;
    const float* w1 = br ? w1b : w1a;
    const float* b1 = br ? b1b : b1a;
    __hip_bfloat16* ys = y + (size_t)slot * NPIX * CH;
    int bid = blockIdx.x;
    int b = bid >> 3, xg = bid & 7;
    int tid = threadIdx.x, wave = tid >> 6, lane = tid & 63;
    int x = xg * XT + wave;
    size_t rowbase = ((size_t)b * NN + x) * NN;
    int chseg = (lane & 15) * 8;
    int ysub = lane >> 4;
    float wv[8], bb[8];
    #pragma unroll
    for (int j = 0; j < 8; ++j) { wv[j] = w1[chseg + j]; bb[j] = b1[chseg + j]; }
    float rs[8] = {};
    for (int g = 0; g < 16; ++g) {
        int yy = g * 4 + ysub;
        float cv = channel[rowbase + yy];
        unsigned pk[4];
        #pragma unroll
        for (int k = 0; k < 4; ++k) {
            float v0 = fmaxf(wv[2 * k] * cv + bb[2 * k], 0.f);
            float v1 = fmaxf(wv[2 * k + 1] * cv + bb[2 * k + 1], 0.f);
            rs[2 * k] += v0; rs[2 * k + 1] += v1;
            pk[k] = (unsigned)bfr(v0) | ((unsigned)bfr(v1) << 16);
        }
        *reinterpret_cast<uint4*>(ys + (rowbase + yy) * CH + chseg) = *reinterpret_cast<const uint4*>(pk);
    }
    if (chseg >= 64) {
        #pragma unroll
        for (int j = 0; j < 8; ++j) {
            rs[j] += __shfl_xor(rs[j], 16, 64);
            rs[j] += __shfl_xor(rs[j], 32, 64);
        }
        if (ysub == 0) {
            float* rp = rowsum + ((size_t)slot * BB * NN + (size_t)b * NN + x) * 64 + (chseg - 64);
            #pragma unroll
            for (int j = 0; j < 8; ++j) rp[j] = rs[j];
        }
    }
}

// ---------- colsum pass: register-accumulated, coalesced; also tot3 partials ----------
__global__ __launch_bounds__(256) void colsumk(const __hip_bfloat16* y, const float* rowsum,
                                               float* colq, float* tot3q) {
    int slot = blockIdx.y;
    const __hip_bfloat16* ys = y + (size_t)slot * NPIX * CH;
    int bid = blockIdx.x;
    int b = bid >> 2, q = bid & 3;
    int t = threadIdx.x;
    int yc = t >> 2, s = t & 3;
    float acc1[8] = {}, acc3[8] = {};
    size_t pix0 = ((size_t)b * NN + q * 16) * NN + yc;
    const __hip_bfloat16* p1 = ys + pix0 * CH + 32 + s * 8;
    const __hip_bfloat16* p3 = ys + pix0 * CH + 96 + s * 8;
    #pragma unroll 4
    for (int xx = 0; xx < 16; ++xx) {
        uint4 u1 = *reinterpret_cast<const uint4*>(p1 + (size_t)xx * NN * CH);
        uint4 u3 = *reinterpret_cast<const uint4*>(p3 + (size_t)xx * NN * CH);
        const unsigned* a1 = &u1.x; const unsigned* a3 = &u3.x;
        #pragma unroll
        for (int k = 0; k < 4; ++k) {
            acc1[2 * k]     += __uint_as_float(a1[k] << 16);
            acc1[2 * k + 1] += __uint_as_float(a1[k] & 0xffff0000u);
            acc3[2 * k]     += __uint_as_float(a3[k] << 16);
            acc3[2 * k + 1] += __uint_as_float(a3[k] & 0xffff0000u);
        }
    }
    float* cq = colq + ((((size_t)slot * BB + b) * 4 + q) * NN + yc) * 64;
    #pragma unroll
    for (int j = 0; j < 8; ++j) { cq[s * 8 + j] = acc1[j]; cq[32 + s * 8 + j] = acc3[j]; }
    if (t < 32) {
        float s2 = 0.f;
        const float* rp = rowsum + ((size_t)slot * BB * NN + (size_t)b * NN + q * 16) * 64 + 32 + t;
        for (int xx = 0; xx < 16; ++xx) s2 += rp[xx * 64];
        tot3q[(((size_t)slot * BB + b) * 4 + q) * 32 + t] = s2;
    }
}

// ---------- bias prep as register-tiled small GEMM ----------
__global__ __launch_bounds__(512) void pb2(const float* bA, const float* bB,
        const float* Mbuf, const float* rowsum, const float* colq, const float* tot3q,
        float* rowbias, float* colbias, int lidx, int br0) {
    int slot = blockIdx.y; int br = br0 + slot;
    int set = br * 3 + lidx;
    const float* M = Mbuf + (size_t)set * 160 * 128;
    const float* bvv = br ? bB : bA;
    int bid = blockIdx.x;                       // 0..127: b = bid&63, type = bid>>6
    int b = bid & 63, type = bid >> 6;
    int t = threadIdx.x; int o = t & 127, g = t >> 7;   // g 0..3
    __shared__ float As[64][65];
    __shared__ float t3[32];
    if (type == 0) {
        const float* rsb = rowsum + ((size_t)slot * BB * NN + (size_t)b * NN) * 64;
        for (int i = t; i < 4096; i += 512) As[i >> 6][i & 63] = rsb[i];
        if (t < 32) {
            float s = 0.f;
            #pragma unroll
            for (int q = 0; q < 4; ++q) s += tot3q[(((size_t)slot * BB + b) * 4 + q) * 32 + t];
            t3[t] = s;
        }
        __syncthreads();
        float acc[16];
        float bvo = bvv[o];
        #pragma unroll
        for (int xi = 0; xi < 16; ++xi) acc[xi] = bvo;
        for (int c = 0; c < 64; ++c) {
            float m = M[c * 128 + o];
            #pragma unroll
            for (int xi = 0; xi < 16; ++xi) acc[xi] += As[g * 16 + xi][c] * m;
        }
        for (int c = 0; c < 32; ++c) {
            float m = M[(64 + c) * 128 + o] * t3[c];
            #pragma unroll
            for (int xi = 0; xi < 16; ++xi) acc[xi] += m;
        }
        for (int xi = 0; xi < 16; ++xi)
            rowbias[(size_t)slot * BB * NN * CH + ((size_t)b * NN + g * 16 + xi) * CH + o] = acc[xi];
    } else {
        for (int i = t; i < 4096; i += 512) {
            float s = 0.f;
            #pragma unroll
            for (int q = 0; q < 4; ++q)
                s += colq[((((size_t)slot * BB + b) * 4 + q) * NN) * 64 + i];
            As[i >> 6][i & 63] = s;
        }
        __syncthreads();
        float acc[16] = {};
        for (int c = 0; c < 64; ++c) {
            float m = M[(96 + c) * 128 + o];
            #pragma unroll
            for (int yi = 0; yi < 16; ++yi) acc[yi] += As[g * 16 + yi][c] * m;
        }
        for (int yi = 0; yi < 16; ++yi)
            colbias[(size_t)slot * BB * NN * CH + ((size_t)b * NN + g * 16 + yi) * CH + o] = acc[yi];
    }
}

// ---------- fused conv+post GEMM: swizzled W LDS, wf reused x2, direct stores ----------
__global__ __launch_bounds__(256, 4) void layerk(
        __hip_bfloat16* y, const __hip_bfloat16* Wp, const float* w0buf, int lidx,
        const float* rowbias, const float* colbias, const float* channel,
        float* rowsum, int br0) {
    int slot = blockIdx.y, br = br0 + slot;
    int set = br * 3 + lidx;
    const __hip_bfloat16* Wl = Wp + (size_t)set * CH * CH;
    const float* w0p = w0buf + set * 128;
    __hip_bfloat16* ys = y + (size_t)slot * NPIX * CH;
    int bid = blockIdx.x;
    int b = bid >> 4, xg = bid & 15;
    int tid = threadIdx.x, wave = tid >> 6, lane = tid & 63;
    int rg = lane >> 4, l16 = lane & 15;
    int x = xg * XTL + wave;
    size_t rowbase = ((size_t)b * NN + x) * NN;

    __shared__ __hip_bfloat16 Ws[CH * CH];          // XOR-swizzled 16B chunks

    #pragma unroll
    for (int it = 0; it < 8; ++it) {                // stage W': 128 rows x 16 chunks
        int i = it * 256 + tid;
        int r = i >> 4, c = i & 15;
        int cs = (c & 8) | ((c ^ r) & 7);
        *reinterpret_cast<uint4*>(&Ws[r * CH + cs * 8]) =
            *reinterpret_cast<const uint4*>(Wl + r * CH + c * 8);
    }

    const float* rb  = rowbias + ((size_t)slot * BB * NN + (size_t)b * NN + x) * CH;
    const float* cbB = colbias + (((size_t)slot * BB + b) * NN) * CH;
    float* rsout = rowsum + ((size_t)slot * BB * NN + (size_t)b * NN + x) * 64;

    float chv[4];
    #pragma unroll
    for (int p = 0; p < 4; ++p) chv[p] = channel[rowbase + p * 16 + l16];
    __syncthreads();

    float rs16[4][4] = {};
    #pragma unroll
    for (int s = 0; s < 2; ++s) {                   // 2 super-iters, 2 pixel groups each
        int pA = 2 * s, pB = 2 * s + 1;
        bfv8 bfA[4], bfB[4];
        #pragma unroll
        for (int ks = 0; ks < 4; ++ks) {
            bfA[ks] = *reinterpret_cast<const bfv8*>(
                ys + (rowbase + pA * 16 + l16) * CH + ks * 32 + rg * 8);
            bfB[ks] = *reinterpret_cast<const bfv8*>(
                ys + (rowbase + pB * 16 + l16) * CH + ks * 32 + rg * 8);
        }
        float cvA = chv[pA], cvB = chv[pB];
        #pragma unroll
        for (int oc = 0; oc < 8; ++oc) {
            bfv8 wf[4];
            #pragma unroll
            for (int ks = 0; ks < 4; ++ks) {
                int chunk = ks * 4 + rg;
                int cs = (chunk & 8) | ((chunk ^ l16) & 7);
                wf[ks] = *reinterpret_cast<const bfv8*>(&Ws[(oc * 16 + l16) * CH + cs * 8]);
            }
            fv4 accA = {0.f, 0.f, 0.f, 0.f}, accB = {0.f, 0.f, 0.f, 0.f};
            #pragma unroll
            for (int ks = 0; ks < 4; ++ks) {
                accA = __builtin_amdgcn_mfma_f32_16x16x32_bf16(wf[ks], bfA[ks], accA, 0, 0, 0);
                accB = __builtin_amdgcn_mfma_f32_16x16x32_bf16(wf[ks], bfB[ks], accB, 0, 0, 0);
            }
            fv4 rbv = *reinterpret_cast<const fv4*>(rb + oc * 16 + rg * 4);
            fv4 w0v = *reinterpret_cast<const fv4*>(w0p + oc * 16 + rg * 4);
            fv4 cbA = *reinterpret_cast<const fv4*>(cbB + (size_t)(pA * 16 + l16) * CH + oc * 16 + rg * 4);
            fv4 cbBv = *reinterpret_cast<const fv4*>(cbB + (size_t)(pB * 16 + l16) * CH + oc * 16 + rg * 4);
            float vA[4], vB[4];
            #pragma unroll
            for (int j = 0; j < 4; ++j) {
                vA[j] = fmaxf(accA[j] + w0v[j] * cvA + rbv[j] + cbA[j], 0.f);
                vB[j] = fmaxf(accB[j] + w0v[j] * cvB + rbv[j] + cbBv[j], 0.f);
            }
            uint2 pkA = {(unsigned)bfr(vA[0]) | ((unsigned)bfr(vA[1]) << 16),
                         (unsigned)bfr(vA[2]) | ((unsigned)bfr(vA[3]) << 16)};
            uint2 pkB = {(unsigned)bfr(vB[0]) | ((unsigned)bfr(vB[1]) << 16),
                         (unsigned)bfr(vB[2]) | ((unsigned)bfr(vB[3]) << 16)};
            *reinterpret_cast<uint2*>(ys + (rowbase + pA * 16 + l16) * CH + oc * 16 + rg * 4) = pkA;
            *reinterpret_cast<uint2*>(ys + (rowbase + pB * 16 + l16) * CH + oc * 16 + rg * 4) = pkB;
            if (oc >= 4) {
                #pragma unroll
                for (int j = 0; j < 4; ++j) rs16[oc - 4][j] += vA[j] + vB[j];
            }
        }
    }
    #pragma unroll
    for (int oc4 = 0; oc4 < 4; ++oc4) {
        #pragma unroll
        for (int m = 1; m < 16; m <<= 1)
            #pragma unroll
            for (int j = 0; j < 4; ++j) rs16[oc4][j] += __shfl_xor(rs16[oc4][j], m, 64);
        if (l16 == 0) {
            fv4 o4 = {rs16[oc4][0], rs16[oc4][1], rs16[oc4][2], rs16[oc4][3]};
            *reinterpret_cast<fv4*>(rsout + oc4 * 16 + rg * 4) = o4;
        }
    }
}

// ---------- final layer (diag only) ----------
__global__ void fin(const __hip_bfloat16* y4, const float* rowsum, const float* colq,
                    const float* tot3q,
                    const float* w5A, const float* w5B, const float* b5A, const float* b5B,
                    const float* channel, float* outbr, int br0) {
    int slot = blockIdx.y; int br = br0 + slot;
    const float* w5 = br ? w5B : w5A;
    float b5 = (br ? b5B : b5A)[0];
    const __hip_bfloat16* ys = y4 + (size_t)slot * NPIX * CH;
    const float* rs = rowsum + (size_t)slot * BB * NN * 64;
    int b = blockIdx.x;
    int xth = threadIdx.x;                      // 0..63
    __shared__ float tot3[32];
    __shared__ float csm[NN * 65];
    for (int i = xth; i < 4096; i += 64) {
        float s = 0.f;
        #pragma unroll
        for (int q = 0; q < 4; ++q)
            s += colq[(((size_t)slot * BB + b) * 4 + q) * NN * 64 + i];
        csm[(i >> 6) * 65 + (i & 63)] = s;
    }
    if (xth < 32) {
        float s = 0.f;
        #pragma unroll
        for (int q = 0; q < 4; ++q) s += tot3q[(((size_t)slot * BB + b) * 4 + q) * 32 + xth];
        tot3[xth] = s;
    }
    __syncthreads();
    size_t pix = (size_t)b * PIX_PER_B + (size_t)xth * NN + xth;
    const __hip_bfloat16* yv = ys + pix * CH;
    const float* rrow = rs + (size_t)(b * NN + xth) * 64;
    const float* crow = &csm[xth * 65];
    float acc = b5 + w5[0] * channel[pix];
    for (int c = 0; c < 32; ++c) {
        acc += w5[1 + c]  * __bfloat162float(yv[c]);
        acc += w5[33 + c] * (crow[c] - __bfloat162float(yv[32 + c])) * INV63;
        acc += w5[65 + c] * (rrow[c] - __bfloat162float(yv[64 + c])) * INV63;
        acc += w5[97 + c] * (tot3[c] - rrow[32 + c] - crow[32 + c] + __bfloat162float(yv[96 + c])) * INV3969;
    }
    outbr[(size_t)br * BB * NN + (size_t)b * NN + xth] = acc;
}

// ---------- combine ----------
__global__ void combine(const float* outbr, const float* u, float* out) {
    int b = blockIdx.x, x = threadIdx.x;
    float av = outbr[b * NN + x] - 2.0f;
    float bv = outbr[BB * NN + b * NN + x] + 4.0f;
    bv = fmaxf(bv, 1e-8f);
    float high = av + bv;
    float action = av + bv * u[b * NN + x];
    float s = logf(bv);
    for (int m = 32; m; m >>= 1) s += __shfl_xor(s, m, 64);
    out[b * NN + x] = action;                   // action  [0,4096)
    if (x == 0) out[BB * NN + b] = s;           // entropy [4096,4160)
    out[BB * NN + BB + b * NN + x] = av;        // a       [4160,8256)
    out[2 * BB * NN + BB + b * NN + x] = high;  // high    [8256,12352)
}

extern "C" void kernel_launch(void* const* d_in, const int* in_sizes, int n_in,
                              void* d_out, int out_size, void* d_ws, size_t ws_size,
                              hipStream_t stream) {
    const float* channel = (const float*)d_in[0];
    const float* u = (const float*)d_in[1];
    const float* w[2][5]; const float* bv[2][5];
    for (int br = 0; br < 2; ++br)
        for (int l = 0; l < 5; ++l) {
            w[br][l]  = (const float*)d_in[2 + br * 10 + l * 2];
            bv[br][l] = (const float*)d_in[3 + br * 10 + l * 2];
        }

    char* p = (char*)d_ws;
    auto alloc = [&](size_t bytes) { char* r = p; p += (bytes + 255) & ~255ull; return r; };
    size_t ybytes    = (size_t)NPIX * CH * 2;                 // 67.1 MB
    size_t rowsum_b  = (size_t)BB * NN * 64 * 4;              // 1 MB
    size_t colq_b    = (size_t)BB * 4 * NN * 64 * 4;          // 4.2 MB
    size_t tot3q_b   = (size_t)BB * 4 * 32 * 4;               // 32 KB
    size_t bias_b    = (size_t)BB * NN * CH * 4;              // 2 MB
    size_t per_slot  = ybytes + rowsum_b + colq_b + tot3q_b + 2 * bias_b;
    size_t fixed     = 6 * CH * CH * 2 + 6 * 160 * 128 * 4 + 6 * 128 * 4 + 2 * BB * NN * 4 + 65536;
    int nslot = (ws_size >= fixed + 2 * per_slot) ? 2 : 1;

    __hip_bfloat16* Wp = (__hip_bfloat16*)alloc(6 * CH * CH * 2);
    float* Mbuf  = (float*)alloc(6 * 160 * 128 * 4);
    float* w0buf = (float*)alloc(6 * 128 * 4);
    float* outbr = (float*)alloc(2 * BB * NN * 4);
    __hip_bfloat16* yb = (__hip_bfloat16*)alloc((size_t)nslot * ybytes);
    float* rowsum  = (float*)alloc((size_t)nslot * rowsum_b);
    float* colq    = (float*)alloc((size_t)nslot * colq_b);
    float* tot3q   = (float*)alloc((size_t)nslot * tot3q_b);
    float* rowbias = (float*)alloc((size_t)nslot * bias_b);
    float* colbias = (float*)alloc((size_t)nslot * bias_b);

    wprep<<<6, 256, 0, stream>>>(w[0][1], w[0][2], w[0][3], w[1][1], w[1][2], w[1][3],
                                 Wp, Mbuf, w0buf);

    int npass = (nslot == 2) ? 1 : 2;
    for (int ps = 0; ps < npass; ++ps) {
        int br0 = (nslot == 2) ? 0 : ps;
        e1k<<<dim3(BB * XT, nslot), 512, 0, stream>>>(channel, w[0][0], bv[0][0], w[1][0], bv[1][0],
                                                      yb, rowsum, br0);
        colsumk<<<dim3(BB * 4, nslot), 256, 0, stream>>>(yb, rowsum, colq, tot3q);
        for (int l = 0; l < 3; ++l) {
            pb2<<<dim3(2 * BB, nslot), 512, 0, stream>>>(bv[0][l + 1], bv[1][l + 1], Mbuf,
                                                         rowsum, colq, tot3q, rowbias, colbias, l, br0);
            layerk<<<dim3(BB * 16, nslot), 256, 0, stream>>>(yb, Wp, w0buf, l,
                                                             rowbias, colbias, channel, rowsum, br0);
            colsumk<<<dim3(BB * 4, nslot), 256, 0, stream>>>(yb, rowsum, colq, tot3q);
        }
        fin<<<dim3(BB, nslot), 64, 0, stream>>>(yb, rowsum, colq, tot3q, w[0][4], w[1][4], bv[0][4], bv[1][4],
                                                channel, outbr, br0);
    }
    combine<<<BB, 64, 0, stream>>>(outbr, u, (float*)d_out);
}

// Round 7
// 377.047 us; speedup vs baseline: 1.2297x; 1.2297x over previous
//
#include <hip/hip_runtime.h>
#include <hip/hip_bf16.h>

#define BB 64
#define NN 64
#define CH 128
#define ICI 129
#define PIX_PER_B (NN*NN)
#define NPIX (BB*PIX_PER_B)
#define INV63 (1.0f/63.0f)
#define INV3969 (1.0f/3969.0f)

typedef __attribute__((ext_vector_type(8))) __bf16 bfv8;
typedef __attribute__((ext_vector_type(4))) float fv4;

__device__ inline unsigned short bfr(float x) {
    __hip_bfloat16 h = __float2bfloat16(x);
    return *reinterpret_cast<unsigned short*>(&h);
}

// ---------- weight transform: Wp (bf16 GEMM weights), M (bias GEMM weights), w0 ----------
__global__ void wprep(const float* w2a, const float* w3a, const float* w4a,
                      const float* w2b, const float* w3b, const float* w4b,
                      __hip_bfloat16* Wp, float* Mbuf, float* w0buf) {
    int bid = blockIdx.x;           // 0..5 = br*3+l
    int br = bid / 3, l = bid % 3;
    const float* w = (br == 0) ? (l == 0 ? w2a : (l == 1 ? w3a : w4a))
                               : (l == 0 ? w2b : (l == 1 ? w3b : w4b));
    __hip_bfloat16* dst = Wp + (size_t)bid * CH * CH;
    for (int idx = threadIdx.x; idx < CH * CH; idx += blockDim.x) {
        int o = idx >> 7, j = idx & 127;
        int c = j & 31, grp = j >> 5;
        float v;
        if (grp == 0)      v =  w[o * ICI + 1 + c];
        else if (grp == 1) v = -w[o * ICI + 33 + c] * INV63;
        else if (grp == 2) v = -w[o * ICI + 65 + c] * INV63;
        else               v =  w[o * ICI + 97 + c] * INV3969;
        dst[idx] = __float2bfloat16(v);
    }
    float* M = Mbuf + (size_t)bid * 160 * 128;
    for (int idx = threadIdx.x; idx < 160 * 128; idx += blockDim.x) {
        int c = idx >> 7, o = idx & 127;
        float v;
        if (c < 32)       v =  w[o * ICI + 65 + c] * INV63;
        else if (c < 64)  v = -w[o * ICI + 97 + (c - 32)] * INV3969;
        else if (c < 96)  v =  w[o * ICI + 97 + (c - 64)] * INV3969;
        else if (c < 128) v =  w[o * ICI + 33 + (c - 96)] * INV63;
        else              v = -w[o * ICI + 97 + (c - 128)] * INV3969;
        M[idx] = v;
    }
    if (threadIdx.x < 128) w0buf[bid * 128 + threadIdx.x] = w[threadIdx.x * ICI];
}

// ---------- red1: rowsum + colsum of (recomputed) layer-1 output, from channel ----------
__global__ __launch_bounds__(256) void red1(const float* channel,
        const float* w1a, const float* b1a, const float* w1b, const float* b1b,
        float* rowsum, float* colpart, int br0) {
    int slot = blockIdx.y, br = br0 + slot;
    const float* w1 = br ? w1b : w1a;
    const float* b1 = br ? b1b : b1a;
    int b = blockIdx.x;
    int t = threadIdx.x;
    __shared__ float chs[64][65];
    for (int i = t; i < 4096; i += 256) chs[i >> 6][i & 63] = channel[(size_t)b * 4096 + i];
    __syncthreads();
    int r = t >> 2, s = t & 3;
    // rowsum: x=r, ch = 64 + s*16 + k
    {
        float wreg[16], breg[16], acc[16] = {};
        #pragma unroll
        for (int k = 0; k < 16; ++k) { wreg[k] = w1[64 + s * 16 + k]; breg[k] = b1[64 + s * 16 + k]; }
        for (int yy = 0; yy < 64; ++yy) {
            float cv = chs[r][yy];
            #pragma unroll
            for (int k = 0; k < 16; ++k) acc[k] += fmaxf(wreg[k] * cv + breg[k], 0.f);
        }
        float* rp = rowsum + ((size_t)slot * BB * NN + (size_t)b * NN + r) * 64 + s * 16;
        #pragma unroll
        for (int k = 0; k < 16; ++k) rp[k] = acc[k];
    }
    // colsum: yc=r, ch = s<2 ? 32+s*16+k : 96+(s-2)*16+k ; c64 = s*16+k
    {
        int chb = (s < 2) ? (32 + s * 16) : (96 + (s - 2) * 16);
        float wreg[16], breg[16], acc[16] = {};
        #pragma unroll
        for (int k = 0; k < 16; ++k) { wreg[k] = w1[chb + k]; breg[k] = b1[chb + k]; }
        for (int xx = 0; xx < 64; ++xx) {
            float cv = chs[xx][r];
            #pragma unroll
            for (int k = 0; k < 16; ++k) acc[k] += fmaxf(wreg[k] * cv + breg[k], 0.f);
        }
        float* cp = colpart + (((size_t)slot * BB + b) * 8 + 0) * 4096 + (size_t)r * 64 + s * 16;
        #pragma unroll
        for (int k = 0; k < 16; ++k) cp[k] = acc[k];
    }
}

// ---------- bias prep as register-tiled small GEMM (tot3 computed in-kernel) ----------
__global__ __launch_bounds__(512) void pb2(const float* bA, const float* bB,
        const float* Mbuf, const float* rowsum, const float* colpart,
        float* rowbias, float* colbias, int lidx, int br0, int nxg) {
    int slot = blockIdx.y; int br = br0 + slot;
    int set = br * 3 + lidx;
    const float* M = Mbuf + (size_t)set * 160 * 128;
    const float* bvv = br ? bB : bA;
    int bid = blockIdx.x;
    int b = bid & 63, type = bid >> 6;
    int t = threadIdx.x; int o = t & 127, g = t >> 7;   // g 0..3
    __shared__ float As[64][65];
    __shared__ float t3[32];
    if (type == 0) {
        const float* rsb = rowsum + ((size_t)slot * BB * NN + (size_t)b * NN) * 64;
        for (int i = t; i < 4096; i += 512) As[i >> 6][i & 63] = rsb[i];
        __syncthreads();
        if (t < 32) {
            float s = 0.f;
            for (int xx = 0; xx < 64; ++xx) s += As[xx][32 + t];
            t3[t] = s;
        }
        __syncthreads();
        float acc[16];
        float bvo = bvv[o];
        #pragma unroll
        for (int xi = 0; xi < 16; ++xi) acc[xi] = bvo;
        for (int c = 0; c < 64; ++c) {
            float m = M[c * 128 + o];
            #pragma unroll
            for (int xi = 0; xi < 16; ++xi) acc[xi] += As[g * 16 + xi][c] * m;
        }
        for (int c = 0; c < 32; ++c) {
            float m = M[(64 + c) * 128 + o] * t3[c];
            #pragma unroll
            for (int xi = 0; xi < 16; ++xi) acc[xi] += m;
        }
        for (int xi = 0; xi < 16; ++xi)
            rowbias[(size_t)slot * BB * NN * CH + ((size_t)b * NN + g * 16 + xi) * CH + o] = acc[xi];
    } else {
        const float* cpb = colpart + ((size_t)slot * BB + b) * 8 * 4096;
        for (int i = t; i < 4096; i += 512) {
            float s = 0.f;
            for (int xg = 0; xg < nxg; ++xg) s += cpb[(size_t)xg * 4096 + i];
            As[i >> 6][i & 63] = s;
        }
        __syncthreads();
        float acc[16] = {};
        for (int c = 0; c < 64; ++c) {
            float m = M[(96 + c) * 128 + o];
            #pragma unroll
            for (int yi = 0; yi < 16; ++yi) acc[yi] += As[g * 16 + yi][c] * m;
        }
        for (int yi = 0; yi < 16; ++yi)
            colbias[(size_t)slot * BB * NN * CH + ((size_t)b * NN + g * 16 + yi) * CH + o] = acc[yi];
    }
}

// ---------- fused conv+post GEMM: l0 computes y1 on-the-fly; colsum fused via outt ----------
__global__ __launch_bounds__(512, 4) void layerk(
        __hip_bfloat16* y, const __hip_bfloat16* Wp, const float* w0buf, int lidx,
        const float* rowbias, const float* colbias, const float* channel,
        const float* w1A, const float* b1A, const float* w1B, const float* b1B,
        float* rowsum, float* colpart, int br0) {
    int slot = blockIdx.y, br = br0 + slot;
    int set = br * 3 + lidx;
    const __hip_bfloat16* Wl = Wp + (size_t)set * CH * CH;
    const float* w0p = w0buf + set * 128;
    __hip_bfloat16* ys = y + (size_t)slot * NPIX * CH;
    int bid = blockIdx.x;
    int b = bid >> 3, xg = bid & 7;
    int tid = threadIdx.x, wave = tid >> 6, lane = tid & 63;
    int rg = lane >> 4, l16 = lane & 15;
    int x = xg * 8 + wave;
    size_t rowbase = ((size_t)b * NN + x) * NN;

    __shared__ __hip_bfloat16 Ws[CH * CH];          // XOR-swizzled 16B chunks
    __shared__ __hip_bfloat16 outt[8][16][136];     // per-wave store-staging tile
    __shared__ float w1s[CH], b1s[CH];

    #pragma unroll
    for (int it = 0; it < 4; ++it) {                // stage W': 128 rows x 16 chunks
        int i = it * 512 + tid;
        int r = i >> 4, c = i & 15;
        int cs = (c & 8) | ((c ^ r) & 7);
        *reinterpret_cast<uint4*>(&Ws[r * CH + cs * 8]) =
            *reinterpret_cast<const uint4*>(Wl + r * CH + c * 8);
    }
    if (lidx == 0 && tid < 128) {
        w1s[tid] = (br ? w1B : w1A)[tid];
        b1s[tid] = (br ? b1B : b1A)[tid];
    }

    const float* rb  = rowbias + ((size_t)slot * BB * NN + (size_t)b * NN + x) * CH;
    const float* cbB = colbias + (((size_t)slot * BB + b) * NN) * CH;
    float* rsout = rowsum + ((size_t)slot * BB * NN + (size_t)b * NN + x) * 64;
    float* cpb = colpart + (((size_t)slot * BB + b) * 8 + xg) * 4096;

    float chv[4];
    #pragma unroll
    for (int p = 0; p < 4; ++p) chv[p] = channel[rowbase + p * 16 + l16];
    __syncthreads();

    float rs16[4][4] = {};
    #pragma unroll
    for (int p = 0; p < 4; ++p) {
        float cv = chv[p];
        bfv8 bfrag[4];
        if (lidx == 0) {                            // y1 on the fly from channel
            #pragma unroll
            for (int ks = 0; ks < 4; ++ks) {
                unsigned pk[4] __attribute__((aligned(16)));
                #pragma unroll
                for (int h = 0; h < 4; ++h) {
                    int ch = ks * 32 + rg * 8 + 2 * h;
                    float v0 = fmaxf(w1s[ch] * cv + b1s[ch], 0.f);
                    float v1 = fmaxf(w1s[ch + 1] * cv + b1s[ch + 1], 0.f);
                    pk[h] = (unsigned)bfr(v0) | ((unsigned)bfr(v1) << 16);
                }
                bfrag[ks] = *reinterpret_cast<const bfv8*>(pk);
            }
        } else {
            #pragma unroll
            for (int ks = 0; ks < 4; ++ks)
                bfrag[ks] = *reinterpret_cast<const bfv8*>(
                    ys + (rowbase + p * 16 + l16) * CH + ks * 32 + rg * 8);
        }
        #pragma unroll
        for (int oc = 0; oc < 8; ++oc) {
            bfv8 wf[4];
            #pragma unroll
            for (int ks = 0; ks < 4; ++ks) {
                int chunk = ks * 4 + rg;
                int cs = (chunk & 8) | ((chunk ^ l16) & 7);
                wf[ks] = *reinterpret_cast<const bfv8*>(&Ws[(oc * 16 + l16) * CH + cs * 8]);
            }
            fv4 acc = {0.f, 0.f, 0.f, 0.f};
            #pragma unroll
            for (int ks = 0; ks < 4; ++ks)
                acc = __builtin_amdgcn_mfma_f32_16x16x32_bf16(wf[ks], bfrag[ks], acc, 0, 0, 0);
            fv4 rbv = *reinterpret_cast<const fv4*>(rb + oc * 16 + rg * 4);
            fv4 w0v = *reinterpret_cast<const fv4*>(w0p + oc * 16 + rg * 4);
            fv4 cbv = *reinterpret_cast<const fv4*>(cbB + (size_t)(p * 16 + l16) * CH + oc * 16 + rg * 4);
            float v[4];
            #pragma unroll
            for (int j = 0; j < 4; ++j)
                v[j] = fmaxf(acc[j] + w0v[j] * cv + rbv[j] + cbv[j], 0.f);
            uint2 pk = {(unsigned)bfr(v[0]) | ((unsigned)bfr(v[1]) << 16),
                        (unsigned)bfr(v[2]) | ((unsigned)bfr(v[3]) << 16)};
            *reinterpret_cast<uint2*>(&outt[wave][l16][oc * 16 + rg * 4]) = pk;
            if (oc >= 4) {
                #pragma unroll
                for (int j = 0; j < 4; ++j) rs16[oc - 4][j] += v[j];
            }
        }
        asm volatile("s_waitcnt lgkmcnt(0)" ::: "memory");
        #pragma unroll
        for (int i4 = 0; i4 < 4; ++i4) {            // coalesced flush: 4 rows x 256B
            uint4 vv = *reinterpret_cast<const uint4*>(&outt[wave][i4 * 4 + rg][l16 * 8]);
            *reinterpret_cast<uint4*>(ys + (rowbase + p * 16 + i4 * 4 + rg) * CH + l16 * 8) = vv;
        }
        __syncthreads();                            // all waves' outt ready
        #pragma unroll
        for (int k = 0; k < 2; ++k) {               // cross-wave colsum partials
            int pi = tid * 2 + k;
            int pix = pi >> 6, c64 = pi & 63;
            int ch = (c64 < 32) ? (32 + c64) : (64 + c64);
            float s = 0.f;
            #pragma unroll
            for (int w = 0; w < 8; ++w) s += __bfloat162float(outt[w][pix][ch]);
            cpb[(size_t)(p * 16 + pix) * 64 + c64] = s;
        }
        __syncthreads();                            // protect outt before next p
    }
    #pragma unroll
    for (int oc4 = 0; oc4 < 4; ++oc4) {             // fused rowsum
        #pragma unroll
        for (int m = 1; m < 16; m <<= 1)
            #pragma unroll
            for (int j = 0; j < 4; ++j) rs16[oc4][j] += __shfl_xor(rs16[oc4][j], m, 64);
        if (l16 == 0) {
            fv4 o4 = {rs16[oc4][0], rs16[oc4][1], rs16[oc4][2], rs16[oc4][3]};
            *reinterpret_cast<fv4*>(rsout + oc4 * 16 + rg * 4) = o4;
        }
    }
}

// ---------- final layer (diag only) ----------
__global__ void fin(const __hip_bfloat16* y4, const float* rowsum, const float* colpart,
                    const float* w5A, const float* w5B, const float* b5A, const float* b5B,
                    const float* channel, float* outbr, int br0) {
    int slot = blockIdx.y; int br = br0 + slot;
    const float* w5 = br ? w5B : w5A;
    float b5 = (br ? b5B : b5A)[0];
    const __hip_bfloat16* ys = y4 + (size_t)slot * NPIX * CH;
    const float* rs = rowsum + (size_t)slot * BB * NN * 64;
    int b = blockIdx.x;
    int xth = threadIdx.x;                      // 0..63
    __shared__ float tot3[32];
    __shared__ float csm[NN * 65];
    const float* cpb = colpart + ((size_t)slot * BB + b) * 8 * 4096;
    for (int i = xth; i < 4096; i += 64) {
        float s = 0.f;
        #pragma unroll
        for (int xg = 0; xg < 8; ++xg) s += cpb[(size_t)xg * 4096 + i];
        csm[(i >> 6) * 65 + (i & 63)] = s;
    }
    if (xth < 32) {
        float s = 0.f;
        for (int xx = 0; xx < 64; ++xx) s += rs[(size_t)(b * NN + xx) * 64 + 32 + xth];
        tot3[xth] = s;
    }
    __syncthreads();
    size_t pix = (size_t)b * PIX_PER_B + (size_t)xth * NN + xth;
    const __hip_bfloat16* yv = ys + pix * CH;
    const float* rrow = rs + (size_t)(b * NN + xth) * 64;
    const float* crow = &csm[xth * 65];
    float acc = b5 + w5[0] * channel[pix];
    for (int c = 0; c < 32; ++c) {
        acc += w5[1 + c]  * __bfloat162float(yv[c]);
        acc += w5[33 + c] * (crow[c] - __bfloat162float(yv[32 + c])) * INV63;
        acc += w5[65 + c] * (rrow[c] - __bfloat162float(yv[64 + c])) * INV63;
        acc += w5[97 + c] * (tot3[c] - rrow[32 + c] - crow[32 + c] + __bfloat162float(yv[96 + c])) * INV3969;
    }
    outbr[(size_t)br * BB * NN + (size_t)b * NN + xth] = acc;
}

// ---------- combine ----------
__global__ void combine(const float* outbr, const float* u, float* out) {
    int b = blockIdx.x, x = threadIdx.x;
    float av = outbr[b * NN + x] - 2.0f;
    float bv = outbr[BB * NN + b * NN + x] + 4.0f;
    bv = fmaxf(bv, 1e-8f);
    float high = av + bv;
    float action = av + bv * u[b * NN + x];
    float s = logf(bv);
    for (int m = 32; m; m >>= 1) s += __shfl_xor(s, m, 64);
    out[b * NN + x] = action;                   // action  [0,4096)
    if (x == 0) out[BB * NN + b] = s;           // entropy [4096,4160)
    out[BB * NN + BB + b * NN + x] = av;        // a       [4160,8256)
    out[2 * BB * NN + BB + b * NN + x] = high;  // high    [8256,12352)
}

extern "C" void kernel_launch(void* const* d_in, const int* in_sizes, int n_in,
                              void* d_out, int out_size, void* d_ws, size_t ws_size,
                              hipStream_t stream) {
    const float* channel = (const float*)d_in[0];
    const float* u = (const float*)d_in[1];
    const float* w[2][5]; const float* bv[2][5];
    for (int br = 0; br < 2; ++br)
        for (int l = 0; l < 5; ++l) {
            w[br][l]  = (const float*)d_in[2 + br * 10 + l * 2];
            bv[br][l] = (const float*)d_in[3 + br * 10 + l * 2];
        }

    char* p = (char*)d_ws;
    auto alloc = [&](size_t bytes) { char* r = p; p += (bytes + 255) & ~255ull; return r; };
    size_t ybytes    = (size_t)NPIX * CH * 2;                 // 67.1 MB
    size_t rowsum_b  = (size_t)BB * NN * 64 * 4;              // 1 MB
    size_t colpart_b = (size_t)BB * 8 * 4096 * 4;             // 8.4 MB
    size_t bias_b    = (size_t)BB * NN * CH * 4;              // 2 MB
    size_t per_slot  = ybytes + rowsum_b + colpart_b + 2 * bias_b;
    size_t fixed     = 6 * CH * CH * 2 + 6 * 160 * 128 * 4 + 6 * 128 * 4 + 2 * BB * NN * 4 + 65536;
    int nslot = (ws_size >= fixed + 2 * per_slot) ? 2 : 1;

    __hip_bfloat16* Wp = (__hip_bfloat16*)alloc(6 * CH * CH * 2);
    float* Mbuf  = (float*)alloc(6 * 160 * 128 * 4);
    float* w0buf = (float*)alloc(6 * 128 * 4);
    float* outbr = (float*)alloc(2 * BB * NN * 4);
    __hip_bfloat16* yb = (__hip_bfloat16*)alloc((size_t)nslot * ybytes);
    float* rowsum  = (float*)alloc((size_t)nslot * rowsum_b);
    float* colpart = (float*)alloc((size_t)nslot * colpart_b);
    float* rowbias = (float*)alloc((size_t)nslot * bias_b);
    float* colbias = (float*)alloc((size_t)nslot * bias_b);

    wprep<<<6, 256, 0, stream>>>(w[0][1], w[0][2], w[0][3], w[1][1], w[1][2], w[1][3],
                                 Wp, Mbuf, w0buf);

    int npass = (nslot == 2) ? 1 : 2;
    for (int ps = 0; ps < npass; ++ps) {
        int br0 = (nslot == 2) ? 0 : ps;
        red1<<<dim3(BB, nslot), 256, 0, stream>>>(channel, w[0][0], bv[0][0], w[1][0], bv[1][0],
                                                  rowsum, colpart, br0);
        for (int l = 0; l < 3; ++l) {
            pb2<<<dim3(2 * BB, nslot), 512, 0, stream>>>(bv[0][l + 1], bv[1][l + 1], Mbuf,
                                                         rowsum, colpart, rowbias, colbias, l, br0,
                                                         (l == 0) ? 1 : 8);
            layerk<<<dim3(BB * 8, nslot), 512, 0, stream>>>(yb, Wp, w0buf, l,
                                                            rowbias, colbias, channel,
                                                            w[0][0], bv[0][0], w[1][0], bv[1][0],
                                                            rowsum, colpart, br0);
        }
        fin<<<dim3(BB, nslot), 64, 0, stream>>>(yb, rowsum, colpart, w[0][4], w[1][4], bv[0][4], bv[1][4],
                                                channel, outbr, br0);
    }
    combine<<<BB, 64, 0, stream>>>(outbr, u, (float*)d_out);
}

// Round 11
// 370.053 us; speedup vs baseline: 1.2529x; 1.0189x over previous
//
#include <hip/hip_runtime.h>
#include <hip/hip_bf16.h>

#define BB 64
#define NN 64
#define CH 128
#define ICI 129
#define PIX_PER_B (NN*NN)
#define NPIX (BB*PIX_PER_B)
#define INV63 (1.0f/63.0f)
#define INV3969 (1.0f/3969.0f)

typedef __attribute__((ext_vector_type(8))) __bf16 bfv8;
typedef __attribute__((ext_vector_type(4))) float fv4;

__device__ inline unsigned short bfr(float x) {
    __hip_bfloat16 h = __float2bfloat16(x);
    return *reinterpret_cast<unsigned short*>(&h);
}

// ---------- weight transform: Wp (bf16 GEMM weights), M (bias GEMM weights), w0 ----------
__global__ void wprep(const float* w2a, const float* w3a, const float* w4a,
                      const float* w2b, const float* w3b, const float* w4b,
                      __hip_bfloat16* Wp, float* Mbuf, float* w0buf) {
    int bid = blockIdx.x;           // 0..5 = br*3+l
    int br = bid / 3, l = bid % 3;
    const float* w = (br == 0) ? (l == 0 ? w2a : (l == 1 ? w3a : w4a))
                               : (l == 0 ? w2b : (l == 1 ? w3b : w4b));
    __hip_bfloat16* dst = Wp + (size_t)bid * CH * CH;
    for (int idx = threadIdx.x; idx < CH * CH; idx += blockDim.x) {
        int o = idx >> 7, j = idx & 127;
        int c = j & 31, grp = j >> 5;
        float v;
        if (grp == 0)      v =  w[o * ICI + 1 + c];
        else if (grp == 1) v = -w[o * ICI + 33 + c] * INV63;
        else if (grp == 2) v = -w[o * ICI + 65 + c] * INV63;
        else               v =  w[o * ICI + 97 + c] * INV3969;
        dst[idx] = __float2bfloat16(v);
    }
    float* M = Mbuf + (size_t)bid * 160 * 128;
    for (int idx = threadIdx.x; idx < 160 * 128; idx += blockDim.x) {
        int c = idx >> 7, o = idx & 127;
        float v;
        if (c < 32)       v =  w[o * ICI + 65 + c] * INV63;
        else if (c < 64)  v = -w[o * ICI + 97 + (c - 32)] * INV3969;
        else if (c < 96)  v =  w[o * ICI + 97 + (c - 64)] * INV3969;
        else if (c < 128) v =  w[o * ICI + 33 + (c - 96)] * INV63;
        else              v = -w[o * ICI + 97 + (c - 128)] * INV3969;
        M[idx] = v;
    }
    if (threadIdx.x < 128) w0buf[bid * 128 + threadIdx.x] = w[threadIdx.x * ICI];
}

// ---------- red1: rowsum + colsum of (recomputed) layer-1 output, from channel ----------
__global__ __launch_bounds__(256) void red1(const float* channel,
        const float* w1a, const float* b1a, const float* w1b, const float* b1b,
        float* rowsum, float* colpart, int br0) {
    int slot = blockIdx.y, br = br0 + slot;
    const float* w1 = br ? w1b : w1a;
    const float* b1 = br ? b1b : b1a;
    int b = blockIdx.x;
    int t = threadIdx.x;
    __shared__ float chs[64][65];
    for (int i = t; i < 4096; i += 256) chs[i >> 6][i & 63] = channel[(size_t)b * 4096 + i];
    __syncthreads();
    int r = t >> 2, s = t & 3;
    // rowsum: x=r, ch = 64 + s*16 + k
    {
        float wreg[16], breg[16], acc[16] = {};
        #pragma unroll
        for (int k = 0; k < 16; ++k) { wreg[k] = w1[64 + s * 16 + k]; breg[k] = b1[64 + s * 16 + k]; }
        for (int yy = 0; yy < 64; ++yy) {
            float cv = chs[r][yy];
            #pragma unroll
            for (int k = 0; k < 16; ++k) acc[k] += fmaxf(wreg[k] * cv + breg[k], 0.f);
        }
        float* rp = rowsum + ((size_t)slot * BB * NN + (size_t)b * NN + r) * 64 + s * 16;
        #pragma unroll
        for (int k = 0; k < 16; ++k) rp[k] = acc[k];
    }
    // colsum: yc=r, ch = s<2 ? 32+s*16+k : 96+(s-2)*16+k ; c64 = s*16+k
    {
        int chb = (s < 2) ? (32 + s * 16) : (96 + (s - 2) * 16);
        float wreg[16], breg[16], acc[16] = {};
        #pragma unroll
        for (int k = 0; k < 16; ++k) { wreg[k] = w1[chb + k]; breg[k] = b1[chb + k]; }
        for (int xx = 0; xx < 64; ++xx) {
            float cv = chs[xx][r];
            #pragma unroll
            for (int k = 0; k < 16; ++k) acc[k] += fmaxf(wreg[k] * cv + breg[k], 0.f);
        }
        float* cp = colpart + (((size_t)slot * BB + b) * 8 + 0) * 4096 + (size_t)r * 64 + s * 16;
        #pragma unroll
        for (int k = 0; k < 16; ++k) cp[k] = acc[k];
    }
}

// ---------- bias prep as register-tiled small GEMM (tot3 computed in-kernel) ----------
__global__ __launch_bounds__(512) void pb2(const float* bA, const float* bB,
        const float* Mbuf, const float* rowsum, const float* colpart,
        float* rowbias, float* colbias, int lidx, int br0, int nxg) {
    int slot = blockIdx.y; int br = br0 + slot;
    int set = br * 3 + lidx;
    const float* M = Mbuf + (size_t)set * 160 * 128;
    const float* bvv = br ? bB : bA;
    int bid = blockIdx.x;
    int b = bid & 63, type = bid >> 6;
    int t = threadIdx.x; int o = t & 127, g = t >> 7;   // g 0..3
    __shared__ float As[64][65];
    __shared__ float t3[32];
    if (type == 0) {
        const float* rsb = rowsum + ((size_t)slot * BB * NN + (size_t)b * NN) * 64;
        for (int i = t; i < 4096; i += 512) As[i >> 6][i & 63] = rsb[i];
        __syncthreads();
        if (t < 32) {
            float s = 0.f;
            for (int xx = 0; xx < 64; ++xx) s += As[xx][32 + t];
            t3[t] = s;
        }
        __syncthreads();
        float acc[16];
        float bvo = bvv[o];
        #pragma unroll
        for (int xi = 0; xi < 16; ++xi) acc[xi] = bvo;
        for (int c = 0; c < 64; ++c) {
            float m = M[c * 128 + o];
            #pragma unroll
            for (int xi = 0; xi < 16; ++xi) acc[xi] += As[g * 16 + xi][c] * m;
        }
        for (int c = 0; c < 32; ++c) {
            float m = M[(64 + c) * 128 + o] * t3[c];
            #pragma unroll
            for (int xi = 0; xi < 16; ++xi) acc[xi] += m;
        }
        for (int xi = 0; xi < 16; ++xi)
            rowbias[(size_t)slot * BB * NN * CH + ((size_t)b * NN + g * 16 + xi) * CH + o] = acc[xi];
    } else {
        const float* cpb = colpart + ((size_t)slot * BB + b) * 8 * 4096;
        for (int i = t; i < 4096; i += 512) {
            float s = 0.f;
            for (int xg = 0; xg < nxg; ++xg) s += cpb[(size_t)xg * 4096 + i];
            As[i >> 6][i & 63] = s;
        }
        __syncthreads();
        float acc[16] = {};
        for (int c = 0; c < 64; ++c) {
            float m = M[(96 + c) * 128 + o];
            #pragma unroll
            for (int yi = 0; yi < 16; ++yi) acc[yi] += As[g * 16 + yi][c] * m;
        }
        for (int yi = 0; yi < 16; ++yi)
            colbias[(size_t)slot * BB * NN * CH + ((size_t)b * NN + g * 16 + yi) * CH + o] = acc[yi];
    }
}

// ---------- fused conv+post GEMM: l0 on-the-fly y1; l2 no y-write, fp32 diag capture ----------
__global__ __launch_bounds__(512, 4) void layerk(
        __hip_bfloat16* y, const __hip_bfloat16* Wp, const float* w0buf, int lidx,
        const float* rowbias, const float* colbias, const float* channel,
        const float* w1A, const float* b1A, const float* w1B, const float* b1B,
        float* rowsum, float* colpart, float* ydiag, int br0) {
    int slot = blockIdx.y, br = br0 + slot;
    int set = br * 3 + lidx;
    const __hip_bfloat16* Wl = Wp + (size_t)set * CH * CH;
    const float* w0p = w0buf + set * 128;
    __hip_bfloat16* ys = y + (size_t)slot * NPIX * CH;
    int bid = blockIdx.x;
    int b = bid >> 3, xg = bid & 7;
    int tid = threadIdx.x, wave = tid >> 6, lane = tid & 63;
    int rg = lane >> 4, l16 = lane & 15;
    int x = xg * 8 + wave;
    size_t rowbase = ((size_t)b * NN + x) * NN;

    __shared__ __hip_bfloat16 Ws[CH * CH];          // XOR-swizzled 16B chunks
    __shared__ __hip_bfloat16 outt[8][16][136];     // per-wave store-staging tile
    __shared__ float w1s[CH], b1s[CH];

    #pragma unroll
    for (int it = 0; it < 4; ++it) {                // stage W': 128 rows x 16 chunks
        int i = it * 512 + tid;
        int r = i >> 4, c = i & 15;
        int cs = (c & 8) | ((c ^ r) & 7);
        *reinterpret_cast<uint4*>(&Ws[r * CH + cs * 8]) =
            *reinterpret_cast<const uint4*>(Wl + r * CH + c * 8);
    }
    if (lidx == 0 && tid < 128) {
        w1s[tid] = (br ? w1B : w1A)[tid];
        b1s[tid] = (br ? b1B : b1A)[tid];
    }

    const float* rb  = rowbias + ((size_t)slot * BB * NN + (size_t)b * NN + x) * CH;
    const float* cbB = colbias + (((size_t)slot * BB + b) * NN) * CH;
    float* rsout = rowsum + ((size_t)slot * BB * NN + (size_t)b * NN + x) * 64;
    float* cpb = colpart + (((size_t)slot * BB + b) * 8 + xg) * 4096;
    float* ydg = ydiag + ((size_t)slot * BB * NN + (size_t)b * NN + x) * CH;

    float chv[4];
    #pragma unroll
    for (int p = 0; p < 4; ++p) chv[p] = channel[rowbase + p * 16 + l16];
    __syncthreads();

    float rs16[4][4] = {};
    #pragma unroll
    for (int p = 0; p < 4; ++p) {
        float cv = chv[p];
        bfv8 bfrag[4];
        if (lidx == 0) {                            // y1 on the fly from channel
            #pragma unroll
            for (int ks = 0; ks < 4; ++ks) {
                unsigned pk[4] __attribute__((aligned(16)));
                #pragma unroll
                for (int h = 0; h < 4; ++h) {
                    int ch = ks * 32 + rg * 8 + 2 * h;
                    float v0 = fmaxf(w1s[ch] * cv + b1s[ch], 0.f);
                    float v1 = fmaxf(w1s[ch + 1] * cv + b1s[ch + 1], 0.f);
                    pk[h] = (unsigned)bfr(v0) | ((unsigned)bfr(v1) << 16);
                }
                bfrag[ks] = *reinterpret_cast<const bfv8*>(pk);
            }
        } else {
            #pragma unroll
            for (int ks = 0; ks < 4; ++ks)
                bfrag[ks] = *reinterpret_cast<const bfv8*>(
                    ys + (rowbase + p * 16 + l16) * CH + ks * 32 + rg * 8);
        }
        #pragma unroll
        for (int oc = 0; oc < 8; ++oc) {
            bfv8 wf[4];
            #pragma unroll
            for (int ks = 0; ks < 4; ++ks) {
                int chunk = ks * 4 + rg;
                int cs = (chunk & 8) | ((chunk ^ l16) & 7);
                wf[ks] = *reinterpret_cast<const bfv8*>(&Ws[(oc * 16 + l16) * CH + cs * 8]);
            }
            fv4 acc = {0.f, 0.f, 0.f, 0.f};
            #pragma unroll
            for (int ks = 0; ks < 4; ++ks)
                acc = __builtin_amdgcn_mfma_f32_16x16x32_bf16(wf[ks], bfrag[ks], acc, 0, 0, 0);
            fv4 rbv = *reinterpret_cast<const fv4*>(rb + oc * 16 + rg * 4);
            fv4 w0v = *reinterpret_cast<const fv4*>(w0p + oc * 16 + rg * 4);
            fv4 cbv = *reinterpret_cast<const fv4*>(cbB + (size_t)(p * 16 + l16) * CH + oc * 16 + rg * 4);
            float v[4];
            #pragma unroll
            for (int j = 0; j < 4; ++j)
                v[j] = fmaxf(acc[j] + w0v[j] * cv + rbv[j] + cbv[j], 0.f);
            if (lidx == 2 && p == (x >> 4) && l16 == (x & 15)) {
                fv4 dv = {v[0], v[1], v[2], v[3]};   // fp32 diagonal capture
                *reinterpret_cast<fv4*>(ydg + oc * 16 + rg * 4) = dv;
            }
            uint2 pk = {(unsigned)bfr(v[0]) | ((unsigned)bfr(v[1]) << 16),
                        (unsigned)bfr(v[2]) | ((unsigned)bfr(v[3]) << 16)};
            *reinterpret_cast<uint2*>(&outt[wave][l16][oc * 16 + rg * 4]) = pk;
            if (oc >= 4) {
                #pragma unroll
                for (int j = 0; j < 4; ++j) rs16[oc - 4][j] += v[j];
            }
        }
        asm volatile("s_waitcnt lgkmcnt(0)" ::: "memory");
        if (lidx != 2) {                            // l2: y4 never goes to global
            #pragma unroll
            for (int i4 = 0; i4 < 4; ++i4) {        // coalesced flush: 4 rows x 256B
                uint4 vv = *reinterpret_cast<const uint4*>(&outt[wave][i4 * 4 + rg][l16 * 8]);
                *reinterpret_cast<uint4*>(ys + (rowbase + p * 16 + i4 * 4 + rg) * CH + l16 * 8) = vv;
            }
        }
        __syncthreads();                            // all waves' outt ready
        #pragma unroll
        for (int k = 0; k < 2; ++k) {               // cross-wave colsum partials
            int pi = tid * 2 + k;
            int pix = pi >> 6, c64 = pi & 63;
            int ch = (c64 < 32) ? (32 + c64) : (64 + c64);
            float s = 0.f;
            #pragma unroll
            for (int w = 0; w < 8; ++w) s += __bfloat162float(outt[w][pix][ch]);
            cpb[(size_t)(p * 16 + pix) * 64 + c64] = s;
        }
        __syncthreads();                            // protect outt before next p
    }
    #pragma unroll
    for (int oc4 = 0; oc4 < 4; ++oc4) {             // fused rowsum
        #pragma unroll
        for (int m = 1; m < 16; m <<= 1)
            #pragma unroll
            for (int j = 0; j < 4; ++j) rs16[oc4][j] += __shfl_xor(rs16[oc4][j], m, 64);
        if (l16 == 0) {
            fv4 o4 = {rs16[oc4][0], rs16[oc4][1], rs16[oc4][2], rs16[oc4][3]};
            *reinterpret_cast<fv4*>(rsout + oc4 * 16 + rg * 4) = o4;
        }
    }
}

// ---------- final layer (diag only, fp32 diag buffer) ----------
__global__ void fin(const float* ydiag, const float* rowsum, const float* colpart,
                    const float* w5A, const float* w5B, const float* b5A, const float* b5B,
                    const float* channel, float* outbr, int br0) {
    int slot = blockIdx.y; int br = br0 + slot;
    const float* w5 = br ? w5B : w5A;
    float b5 = (br ? b5B : b5A)[0];
    const float* rs = rowsum + (size_t)slot * BB * NN * 64;
    int b = blockIdx.x;
    int xth = threadIdx.x;                      // 0..63
    __shared__ float tot3[32];
    __shared__ float csm[NN * 65];
    const float* cpb = colpart + ((size_t)slot * BB + b) * 8 * 4096;
    for (int i = xth; i < 4096; i += 64) {
        float s = 0.f;
        #pragma unroll
        for (int xg = 0; xg < 8; ++xg) s += cpb[(size_t)xg * 4096 + i];
        csm[(i >> 6) * 65 + (i & 63)] = s;
    }
    if (xth < 32) {
        float s = 0.f;
        for (int xx = 0; xx < 64; ++xx) s += rs[(size_t)(b * NN + xx) * 64 + 32 + xth];
        tot3[xth] = s;
    }
    __syncthreads();
    const float* yv = ydiag + ((size_t)slot * BB * NN + (size_t)b * NN + xth) * CH;
    const float* rrow = rs + (size_t)(b * NN + xth) * 64;
    const float* crow = &csm[xth * 65];
    float acc = b5 + w5[0] * channel[(size_t)b * PIX_PER_B + (size_t)xth * NN + xth];
    for (int c = 0; c < 32; ++c) {
        acc += w5[1 + c]  * yv[c];
        acc += w5[33 + c] * (crow[c] - yv[32 + c]) * INV63;
        acc += w5[65 + c] * (rrow[c] - yv[64 + c]) * INV63;
        acc += w5[97 + c] * (tot3[c] - rrow[32 + c] - crow[32 + c] + yv[96 + c]) * INV3969;
    }
    outbr[(size_t)br * BB * NN + (size_t)b * NN + xth] = acc;
}

// ---------- combine ----------
__global__ void combine(const float* outbr, const float* u, float* out) {
    int b = blockIdx.x, x = threadIdx.x;
    float av = outbr[b * NN + x] - 2.0f;
    float bv = outbr[BB * NN + b * NN + x] + 4.0f;
    bv = fmaxf(bv, 1e-8f);
    float high = av + bv;
    float action = av + bv * u[b * NN + x];
    float s = logf(bv);
    for (int m = 32; m; m >>= 1) s += __shfl_xor(s, m, 64);
    out[b * NN + x] = action;                   // action  [0,4096)
    if (x == 0) out[BB * NN + b] = s;           // entropy [4096,4160)
    out[BB * NN + BB + b * NN + x] = av;        // a       [4160,8256)
    out[2 * BB * NN + BB + b * NN + x] = high;  // high    [8256,12352)
}

extern "C" void kernel_launch(void* const* d_in, const int* in_sizes, int n_in,
                              void* d_out, int out_size, void* d_ws, size_t ws_size,
                              hipStream_t stream) {
    const float* channel = (const float*)d_in[0];
    const float* u = (const float*)d_in[1];
    const float* w[2][5]; const float* bv[2][5];
    for (int br = 0; br < 2; ++br)
        for (int l = 0; l < 5; ++l) {
            w[br][l]  = (const float*)d_in[2 + br * 10 + l * 2];
            bv[br][l] = (const float*)d_in[3 + br * 10 + l * 2];
        }

    char* p = (char*)d_ws;
    auto alloc = [&](size_t bytes) { char* r = p; p += (bytes + 255) & ~255ull; return r; };
    size_t ybytes    = (size_t)NPIX * CH * 2;                 // 67.1 MB
    size_t rowsum_b  = (size_t)BB * NN * 64 * 4;              // 1 MB
    size_t colpart_b = (size_t)BB * 8 * 4096 * 4;             // 8.4 MB
    size_t bias_b    = (size_t)BB * NN * CH * 4;              // 2 MB
    size_t ydiag_b   = (size_t)BB * NN * CH * 4;              // 2 MB
    size_t per_slot  = ybytes + rowsum_b + colpart_b + 2 * bias_b + ydiag_b;
    size_t fixed     = 6 * CH * CH * 2 + 6 * 160 * 128 * 4 + 6 * 128 * 4 + 2 * BB * NN * 4 + 65536;
    int nslot = (ws_size >= fixed + 2 * per_slot) ? 2 : 1;

    __hip_bfloat16* Wp = (__hip_bfloat16*)alloc(6 * CH * CH * 2);
    float* Mbuf  = (float*)alloc(6 * 160 * 128 * 4);
    float* w0buf = (float*)alloc(6 * 128 * 4);
    float* outbr = (float*)alloc(2 * BB * NN * 4);
    __hip_bfloat16* yb = (__hip_bfloat16*)alloc((size_t)nslot * ybytes);
    float* rowsum  = (float*)alloc((size_t)nslot * rowsum_b);
    float* colpart = (float*)alloc((size_t)nslot * colpart_b);
    float* rowbias = (float*)alloc((size_t)nslot * bias_b);
    float* colbias = (float*)alloc((size_t)nslot * bias_b);
    float* ydiag   = (float*)alloc((size_t)nslot * ydiag_b);

    wprep<<<6, 256, 0, stream>>>(w[0][1], w[0][2], w[0][3], w[1][1], w[1][2], w[1][3],
                                 Wp, Mbuf, w0buf);

    int npass = (nslot == 2) ? 1 : 2;
    for (int ps = 0; ps < npass; ++ps) {
        int br0 = (nslot == 2) ? 0 : ps;
        red1<<<dim3(BB, nslot), 256, 0, stream>>>(channel, w[0][0], bv[0][0], w[1][0], bv[1][0],
                                                  rowsum, colpart, br0);
        for (int l = 0; l < 3; ++l) {
            pb2<<<dim3(2 * BB, nslot), 512, 0, stream>>>(bv[0][l + 1], bv[1][l + 1], Mbuf,
                                                         rowsum, colpart, rowbias, colbias, l, br0,
                                                         (l == 0) ? 1 : 8);
            layerk<<<dim3(BB * 8, nslot), 512, 0, stream>>>(yb, Wp, w0buf, l,
                                                            rowbias, colbias, channel,
                                                            w[0][0], bv[0][0], w[1][0], bv[1][0],
                                                            rowsum, colpart, ydiag, br0);
        }
        fin<<<dim3(BB, nslot), 64, 0, stream>>>(ydiag, rowsum, colpart, w[0][4], w[1][4], bv[0][4], bv[1][4],
                                                channel, outbr, br0);
    }
    combine<<<BB, 64, 0, stream>>>(outbr, u, (float*)d_out);
}